// Round 5
// baseline (230.792 us; speedup 1.0000x reference)
//
#include <hip/hip_runtime.h>
#include <stdint.h>

// IDXST(4096x4096): y[r][k] = sum_n x[r][n] sin(pi*n*(2k+1)/8192).
// R10: R9's read-ahead pipelined 8-phase schedule, with the register-spill
// fixed. R9's __launch_bounds__(512,2) capped the allocator at 128 VGPRs;
// the extra ping-pong fragment sets (+32 VGPR over R6) spilled to scratch:
// FETCH 70->166MB, WRITE 74->153MB, VALUBusy 4%, 196us. The LDS footprint
// (128KiB) already limits occupancy to 1 block/CU (2 waves/SIMD), which
// permits ~256 regs/wave — so the cap bought nothing. R10 = R9 with
// __launch_bounds__(512) only; allocator free, zero spills expected.
// Schedule (unchanged from R9): every fragment ds_read ONE PHASE AHEAD of
// its consuming MFMA (reads/phase 4,8,8,4,...), A ping-pong a0/a1, B
// ping-pong s0/s1, one barrier per phase, vmcnt(0) at p3/p7 only.
// ws (44 MB): xo 16 | xee 8 | xeo 8 | Bo 8 | Bp 2 | Bq 2.

#define NN 4096

typedef __attribute__((ext_vector_type(8))) short short8;
typedef __attribute__((ext_vector_type(4))) float f32x4;

__device__ __forceinline__ unsigned short f2bf(float f) {
  unsigned int u = __float_as_uint(f);
  u += 0x7fffu + ((u >> 16) & 1u);
  return (unsigned short)(u >> 16);
}

__device__ __forceinline__ void async_load16(const void* g, void* lds) {
  __builtin_amdgcn_global_load_lds(
      (const __attribute__((address_space(1))) unsigned int*)g,
      (__attribute__((address_space(3))) unsigned int*)lds, 16, 0, 0);
}

#define NXS (NN * NN / 8)        // 2M x-split threads (8 floats each)
#define NBO (2048 * 2048 / 4)    // 1M Bo threads
#define NBP (1024 * 1024 / 4)    // 256K Bp threads (Bq same)

// prep: xo[r][m]=x[r][2m+1]; xee[r][t]=x[r][4t]; xeo[r][t]=x[r][4t+2];
// Bo[c][m]=sin(pi(2m+1)(2c+1)/8192); Bp[c][t]=sin(pi*t*(2c+1)/2048);
// Bq[c][t]=sin(pi(2t+1)(2c+1)/4096)
__global__ void prep_kernel(const float* __restrict__ x,
                            unsigned short* __restrict__ xo,
                            unsigned short* __restrict__ xee,
                            unsigned short* __restrict__ xeo,
                            unsigned short* __restrict__ Bo,
                            unsigned short* __restrict__ Bp,
                            unsigned short* __restrict__ Bq) {
  int gi = blockIdx.x * blockDim.x + threadIdx.x;
  if (gi < NXS) {
    int g = gi & 511;            // 8-float group in row
    int r = gi >> 9;
    const float4* src = (const float4*)(x + (size_t)r * NN + g * 8);
    float4 v0 = src[0], v1 = src[1];    // n = 8g+0..3, 8g+4..7
    ushort4 ov;                          // odd n -> m = 4g..4g+3
    ov.x = f2bf(v0.y); ov.y = f2bf(v0.w); ov.z = f2bf(v1.y); ov.w = f2bf(v1.w);
    *(ushort4*)&xo[(size_t)r * 2048 + g * 4] = ov;
    unsigned int ee = ((unsigned)f2bf(v1.x) << 16) | f2bf(v0.x);  // t=2g,2g+1
    *(unsigned int*)&xee[(size_t)r * 1024 + g * 2] = ee;
    unsigned int eo = ((unsigned)f2bf(v1.z) << 16) | f2bf(v0.z);
    *(unsigned int*)&xeo[(size_t)r * 1024 + g * 2] = eo;
  } else if (gi < NXS + NBO) {
    int i = gi - NXS;
    int m0 = (i & 511) * 4;
    int c = i >> 9;
    unsigned int tw = 2u * (unsigned)c + 1u;
    const float sc = 3.14159265358979323846f / 8192.0f;
    ushort4 o; unsigned int ph;
    ph = ((unsigned)(2 * (m0 + 0) + 1) * tw) & 16383u; o.x = f2bf(__sinf((float)ph * sc));
    ph = ((unsigned)(2 * (m0 + 1) + 1) * tw) & 16383u; o.y = f2bf(__sinf((float)ph * sc));
    ph = ((unsigned)(2 * (m0 + 2) + 1) * tw) & 16383u; o.z = f2bf(__sinf((float)ph * sc));
    ph = ((unsigned)(2 * (m0 + 3) + 1) * tw) & 16383u; o.w = f2bf(__sinf((float)ph * sc));
    *(ushort4*)&Bo[(size_t)c * 2048 + m0] = o;
  } else if (gi < NXS + NBO + NBP) {
    int i = gi - NXS - NBO;
    int t0 = (i & 255) * 4;
    int c = i >> 8;
    unsigned int tw = 2u * (unsigned)c + 1u;
    const float sc = 3.14159265358979323846f / 2048.0f;
    ushort4 o; unsigned int ph;
    ph = ((unsigned)(t0 + 0) * tw) & 4095u; o.x = f2bf(__sinf((float)ph * sc));
    ph = ((unsigned)(t0 + 1) * tw) & 4095u; o.y = f2bf(__sinf((float)ph * sc));
    ph = ((unsigned)(t0 + 2) * tw) & 4095u; o.z = f2bf(__sinf((float)ph * sc));
    ph = ((unsigned)(t0 + 3) * tw) & 4095u; o.w = f2bf(__sinf((float)ph * sc));
    *(ushort4*)&Bp[(size_t)c * 1024 + t0] = o;
  } else {
    int i = gi - NXS - NBO - NBP;
    int t0 = (i & 255) * 4;
    int c = i >> 8;
    unsigned int tw = 2u * (unsigned)c + 1u;
    const float sc = 3.14159265358979323846f / 4096.0f;
    ushort4 o; unsigned int ph;
    ph = ((unsigned)(2 * (t0 + 0) + 1) * tw) & 8191u; o.x = f2bf(__sinf((float)ph * sc));
    ph = ((unsigned)(2 * (t0 + 1) + 1) * tw) & 8191u; o.y = f2bf(__sinf((float)ph * sc));
    ph = ((unsigned)(2 * (t0 + 2) + 1) * tw) & 8191u; o.z = f2bf(__sinf((float)ph * sc));
    ph = ((unsigned)(2 * (t0 + 3) + 1) * tw) & 8191u; o.w = f2bf(__sinf((float)ph * sc));
    *(ushort4*)&Bq[(size_t)c * 1024 + t0] = o;
  }
}

// ---- 8-phase 256x256 GEMM machinery ------------------------------------
// LDS ushort offsets: region(buf b, mat m(0=A,1=B), half h) = (4b+2m+h)*8192.
#define PH_BAR  __builtin_amdgcn_s_barrier()
#define W_VM4   asm volatile("s_waitcnt vmcnt(4)" ::: "memory")
#define W_VM0   asm volatile("s_waitcnt vmcnt(0)" ::: "memory")
#define PRIO1   __builtin_amdgcn_s_setprio(1)
#define PRIO0   __builtin_amdgcn_s_setprio(0)

// Stage one 128x64 half-tile: rows prow0+half*128+[0,128), k cols [koff,koff+64).
// Linear LDS dest (tid*16B, +8KB for rows 64-127); source chunk pre-swizzled
// by the same chunk^(row&7) involution the ds_reads apply.
#define STAGE(Mat, prow0, koff, half, off) do {                                 \
    const unsigned short* _s =                                                  \
        (Mat) + (size_t)((prow0) + (half) * 128 + st_r) * K + (koff) + st_c;    \
    async_load16(_s, &lds[(off) + tid * 8]);                                    \
    async_load16(_s + (size_t)64 * K, &lds[(off) + 4096 + tid * 8]);            \
  } while (0)

// A-frags for quadrant row-half mh of buffer b into named set SET: 8 reads.
#define LOADA(SET, b, mh) do {                                                  \
    const int _ab = ((b) * 4 + wm) * 8192 + (mh) * 4096 + lr * 64;              \
    _Pragma("unroll") for (int _i = 0; _i < 4; ++_i) {                          \
      SET[_i][0] = *(const short8*)&lds[_ab + _i * 1024 + cA0];                 \
      SET[_i][1] = *(const short8*)&lds[_ab + _i * 1024 + cA1];                 \
    }                                                                           \
  } while (0)

// B-frags for quadrant col-half nh of buffer b into named set SET: 4 reads.
#define LOADB(SET, b, nh) do {                                                  \
    const int _bb = ((b) * 4 + 2 + wnh) * 8192 + wnl * 4096 + (nh) * 2048 +     \
                    lr * 64;                                                    \
    _Pragma("unroll") for (int _j = 0; _j < 2; ++_j) {                          \
      SET[_j][0] = *(const short8*)&lds[_bb + _j * 1024 + cA0];                 \
      SET[_j][1] = *(const short8*)&lds[_bb + _j * 1024 + cA1];                 \
    }                                                                           \
  } while (0)

// One C-quadrant x K=64: 16 MFMA consuming named register sets (loaded in a
// PREVIOUS phase; compiler emits the per-fragment lgkmcnt deps).
#define MMAQ(AS, BS, mh, nh) do {                                               \
    _Pragma("unroll") for (int _k = 0; _k < 2; ++_k)                            \
    _Pragma("unroll") for (int _i = 0; _i < 4; ++_i)                            \
    _Pragma("unroll") for (int _j = 0; _j < 2; ++_j)                            \
      acc[(mh) * 4 + _i][(nh) * 2 + _j] =                                       \
          __builtin_amdgcn_mfma_f32_16x16x32_bf16(                              \
              AS[_i][_k], BS[_j][_k], acc[(mh) * 4 + _i][(nh) * 2 + _j],        \
              0, 0, 0);                                                         \
  } while (0)

__global__ __launch_bounds__(512) void gemm3_kernel(
    const unsigned short* __restrict__ xo,
    const unsigned short* __restrict__ xee,
    const unsigned short* __restrict__ xeo,
    const unsigned short* __restrict__ Bo,
    const unsigned short* __restrict__ Bp,
    const unsigned short* __restrict__ Bq,
    float* __restrict__ out) {
  __shared__ __align__(16) unsigned short lds[65536];   // 128 KiB

  const int bx = blockIdx.x;
  const unsigned short* A;
  const unsigned short* Bm;
  int K, row0, ncol0, col0;
  if (bx < 128) {
    A = xo;  Bm = Bo; K = 2048;
    row0 = (bx & 15) * 256; ncol0 = (bx >> 4) * 256; col0 = ncol0;
  } else if (bx < 192) {
    int b = bx - 128;
    A = xee; Bm = Bp; K = 1024;
    row0 = (b & 15) * 256; ncol0 = (b >> 4) * 256; col0 = 2048 + ncol0;
  } else {
    int b = bx - 192;
    A = xeo; Bm = Bq; K = 1024;
    row0 = (b & 15) * 256; ncol0 = (b >> 4) * 256; col0 = 3072 + ncol0;
  }
  const int NT = K >> 6;           // K-tiles of 64 (32 for U, 16 for P/Q)

  const int tid = threadIdx.x;
  const int lane = tid & 63;
  const int wave = tid >> 6;
  const int wm = wave >> 2;        // 0..1 : 128-row half of C
  const int wn = wave & 3;         // 0..3 : 64-col strip of C
  const int wnh = wn >> 1, wnl = wn & 1;
  const int lr = lane & 15, kq = lane >> 4;
  const int st_r = tid >> 3;                         // staging row 0..63
  const int st_c = ((tid & 7) ^ (st_r & 7)) * 8;     // pre-swizzled src chunk
  const int cA0 = (kq ^ (lr & 7)) * 8;               // swizzled ds_read chunks
  const int cA1 = ((4 + kq) ^ (lr & 7)) * 8;

  f32x4 acc[8][4];
#pragma unroll
  for (int i = 0; i < 8; ++i)
#pragma unroll
    for (int j = 0; j < 4; ++j)
      acc[i][j] = (f32x4){0.f, 0.f, 0.f, 0.f};
  // Named fragment sets (fixed period-1 slot assignment, no runtime indexing):
  short8 a0[4][2], a1[4][2];   // A ping-pong
  short8 s0[2][2], s1[2][2];   // B ping-pong

  // Prologue: buf0 A+B (tile 0), buf1 B (tile 1): 12 loads. vmcnt(4) leaves
  // buf1-B's 4 in flight (steady-state entry invariant = 4 outstanding).
  STAGE(A,  row0,  0,  0, 0);
  STAGE(A,  row0,  0,  1, 8192);
  STAGE(Bm, ncol0, 0,  0, 16384);
  STAGE(Bm, ncol0, 0,  1, 24576);
  STAGE(Bm, ncol0, 64, 0, 49152);
  STAGE(Bm, ncol0, 64, 1, 57344);
  W_VM4; PH_BAR;
  LOADA(a1, 0, 0);               // A(0,0) -> consumed p1/p2
  LOADB(s1, 0, 0);               // B(0,0) -> consumed p1/p4

  const int NITER = NT >> 1;
  for (int it = 0; it < NITER - 1; ++it) {
    const int t64 = it << 7;     // k-offset of tile t = 2*it
    // p1: load B(0,1); stage A[t+1]h0 -> buf1; MFMA q(0,0)b0 {a1,s1}
    LOADB(s0, 0, 1);
    STAGE(A, row0, t64 + 64, 0, 32768);
    PH_BAR; PRIO1; MMAQ(a1, s1, 0, 0); PRIO0;
    // p2: load A(0,1); stage A[t+1]h1; MFMA q(0,1)b0 {a1,s0}
    LOADA(a0, 0, 1);
    STAGE(A, row0, t64 + 64, 1, 40960);
    PH_BAR; PRIO1; MMAQ(a1, s0, 0, 1); PRIO0;
    // p3: drain -> buf1[t+1] resident; load A(1,0); MFMA q(1,1)b0 {a0,s0}
    W_VM0;
    LOADA(a1, 1, 0);
    PH_BAR; PRIO1; MMAQ(a0, s0, 1, 1); PRIO0;
    // p4: load B(1,0); stage B[t+2] both halves -> buf0; MFMA q(1,0)b0 {a0,s1}
    LOADB(s0, 1, 0);
    STAGE(Bm, ncol0, t64 + 128, 0, 16384);
    STAGE(Bm, ncol0, t64 + 128, 1, 24576);
    PH_BAR; PRIO1; MMAQ(a0, s1, 1, 0); PRIO0;
    // p5: load B(1,1); stage A[t+2]h0 -> buf0; MFMA q(0,0)b1 {a1,s0}
    LOADB(s1, 1, 1);
    STAGE(A, row0, t64 + 128, 0, 0);
    PH_BAR; PRIO1; MMAQ(a1, s0, 0, 0); PRIO0;
    // p6: load A(1,1); stage A[t+2]h1; MFMA q(0,1)b1 {a1,s1}
    LOADA(a0, 1, 1);
    STAGE(A, row0, t64 + 128, 1, 8192);
    PH_BAR; PRIO1; MMAQ(a1, s1, 0, 1); PRIO0;
    // p7: drain -> buf0[t+2] resident; load A'(0,0); MFMA q(1,1)b1 {a0,s1}
    W_VM0;
    LOADA(a1, 0, 0);
    PH_BAR; PRIO1; MMAQ(a0, s1, 1, 1); PRIO0;
    // p8: load B'(0,0); stage B[t+3] both halves -> buf1; MFMA q(1,0)b1 {a0,s0}
    LOADB(s1, 0, 0);
    STAGE(Bm, ncol0, t64 + 192, 0, 49152);
    STAGE(Bm, ncol0, t64 + 192, 1, 57344);
    PH_BAR; PRIO1; MMAQ(a0, s0, 1, 0); PRIO0;
  }

  // Peeled last iteration (tiles NT-2 -> buf0, NT-1 -> buf1): only A[NT-1]
  // left to stage; vmcnt(0) at p3 drains everything; no barriers after p3.
  {
    const int t64 = (NT - 2) << 6;
    LOADB(s0, 0, 1);
    STAGE(A, row0, t64 + 64, 0, 32768);
    PH_BAR; PRIO1; MMAQ(a1, s1, 0, 0); PRIO0;
    LOADA(a0, 0, 1);
    STAGE(A, row0, t64 + 64, 1, 40960);
    PH_BAR; PRIO1; MMAQ(a1, s0, 0, 1); PRIO0;
    W_VM0;
    LOADA(a1, 1, 0);
    PH_BAR; PRIO1; MMAQ(a0, s0, 1, 1); PRIO0;
    LOADB(s0, 1, 0);
    PRIO1; MMAQ(a0, s1, 1, 0); PRIO0;
    LOADB(s1, 1, 1);
    PRIO1; MMAQ(a1, s0, 0, 0); PRIO0;
    LOADA(a0, 1, 1);
    PRIO1; MMAQ(a1, s1, 0, 1); PRIO0;
    PRIO1; MMAQ(a0, s1, 1, 1); PRIO0;
    PRIO1; MMAQ(a0, s0, 1, 0); PRIO0;
  }

  // C/D layout: col=lane&15, row=quad*4+reg
#pragma unroll
  for (int i = 0; i < 8; ++i)
#pragma unroll
    for (int j = 0; j < 4; ++j)
#pragma unroll
      for (int r = 0; r < 4; ++r) {
        int row = row0 + wm * 128 + i * 16 + kq * 4 + r;
        int col = col0 + wn * 64 + j * 16 + lr;
        out[(size_t)row * NN + col] = acc[i][j][r];
      }
}

// In-place combine, both fold levels. Row layout on entry:
// [0:2048)=u, [2048:3072)=p, [3072:4096)=q.
// v[k']=p+q, v[2047-k']=q-p (k'<1024); y[k]=v[k]+u[k], y[4095-k]=u[k]-v[k].
__global__ void combine_kernel(float* __restrict__ out) {
  int t = blockIdx.x * blockDim.x + threadIdx.x;   // 4096 rows * 128 threads
  int r = t >> 7;
  int k0 = (t & 127) * 4;                          // [0,512)
  float* row = out + (size_t)r * NN;
  float U0[4], U1[4], U2[4], U3[4], P0[4], P1[4], Q0[4], Q1[4];
  *(float4*)U0 = *(float4*)&row[k0];          // u[k0+e]
  *(float4*)U1 = *(float4*)&row[1020 - k0];   // u[1023-k'] rev
  *(float4*)U2 = *(float4*)&row[1024 + k0];   // u[1024+k0+e]
  *(float4*)U3 = *(float4*)&row[2044 - k0];   // u[2047-k'] rev
  *(float4*)P0 = *(float4*)&row[2048 + k0];   // p[k0+e]
  *(float4*)P1 = *(float4*)&row[3068 - k0];   // p[1023-k'] rev
  *(float4*)Q0 = *(float4*)&row[3072 + k0];   // q[k0+e]
  *(float4*)Q1 = *(float4*)&row[4092 - k0];   // q[1023-k'] rev
  float YA[4], YB[4], YC[4], YD[4], YE[4], YF[4], YG[4], YH[4];
#pragma unroll
  for (int e = 0; e < 4; ++e) {
    float v1 = P0[e] + Q0[e];        // v[k']
    float v2 = Q0[e] - P0[e];        // v[2047-k']
    float um = U3[3 - e];            // u[2047-k']
    YA[e] = v1 + U0[e];              // y[k']
    YB[3 - e] = U0[e] - v1;          // y[4095-k']
    YC[3 - e] = v2 + um;             // y[2047-k']
    YD[e] = um - v2;                 // y[2048+k']
    float pm = P1[3 - e], qm = Q1[3 - e];
    float w1 = pm + qm;              // v[1023-k']
    float w2 = qm - pm;              // v[1024+k']
    float umm = U1[3 - e];           // u[1023-k']
    YE[3 - e] = w1 + umm;            // y[1023-k']
    YF[e] = umm - w1;                // y[3072+k']
    YG[e] = w2 + U2[e];              // y[1024+k']
    YH[3 - e] = U2[e] - w2;          // y[3071-k']
  }
  *(float4*)&row[k0] = *(float4*)YA;
  *(float4*)&row[4092 - k0] = *(float4*)YB;
  *(float4*)&row[2044 - k0] = *(float4*)YC;
  *(float4*)&row[2048 + k0] = *(float4*)YD;
  *(float4*)&row[1020 - k0] = *(float4*)YE;
  *(float4*)&row[3072 + k0] = *(float4*)YF;
  *(float4*)&row[1024 + k0] = *(float4*)YG;
  *(float4*)&row[3068 - k0] = *(float4*)YH;
}

extern "C" void kernel_launch(void* const* d_in, const int* in_sizes, int n_in,
                              void* d_out, int out_size, void* d_ws, size_t ws_size,
                              hipStream_t stream) {
  const float* x = (const float*)d_in[0];
  float* out = (float*)d_out;
  unsigned short* xo  = (unsigned short*)d_ws;            // 16 MB
  unsigned short* xee = xo + (size_t)NN * 2048;           // 8 MB
  unsigned short* xeo = xee + (size_t)NN * 1024;          // 8 MB
  unsigned short* Bo  = xeo + (size_t)NN * 1024;          // 8 MB
  unsigned short* Bp  = Bo + (size_t)2048 * 2048;         // 2 MB
  unsigned short* Bq  = Bp + (size_t)1024 * 1024;         // 2 MB -> 44 MB total

  int prep_threads = NXS + NBO + 2 * NBP;
  prep_kernel<<<prep_threads / 256, 256, 0, stream>>>(x, xo, xee, xeo, Bo, Bp, Bq);

  gemm3_kernel<<<256, 512, 0, stream>>>(xo, xee, xeo, Bo, Bp, Bq, out);

  combine_kernel<<<NN * 128 / 256, 256, 0, stream>>>(out);
}

// Round 6
// 101.253 us; speedup vs baseline: 2.2794x; 2.2794x over previous
//
#include <hip/hip_runtime.h>
#include <stdint.h>

// IDXST(4096x4096): y[r][k] = sum_n x[r][n] sin(pi*n*(2k+1)/8192).
// R11: balanced-makespan grid. R6's 256x256 tiles gave U=128 blocks @268MF
// while P/Q CUs idled half the dispatch (makespan 268 MF/CU; measured 74us
// with phase accounting MFMA 621 + LDS 565 + barrier of 1386 cyc). Schedule
// surgery (R7-R10) failed or spilled; the cheap 25% is PACKING:
//   tiles 256(M)x128(N), LDS 96KB (1 block/CU):
//   U: 16x16=256 blocks @134MF (K=2048), P: 128 @67, Q: 128 @67 -> 512 blocks.
//   U blocks are bx 0..255 -> dispatched first -> EVERY CU runs exactly one
//   U block (round 1), then one P/Q block (round 2): makespan 134+67 = 201
//   MF/CU vs 268 (0.75x), guaranteed by construction.
// Schedule is R6's verified 8-phase with sizes re-derived: A-half-tile = 16KB
// (2 gload_lds/thread), B-half = 8KB (1 load); counted waits become vmcnt(2)
// at p4/p8 (FIFO: entry invariant = B[t+1] 2 loads; p1,p2 +2+2 A[t+1];
// p3,p4 +1+1 B[t+2]; drain-to-2 completes exactly tile t+1). acc shrinks to
// 64 AGPR (per-wave output 128x32) -> no register pressure.
// ws (44 MB): xo 16 | xee 8 | xeo 8 | Bo 8 | Bp 2 | Bq 2.

#define NN 4096

typedef __attribute__((ext_vector_type(8))) short short8;
typedef __attribute__((ext_vector_type(4))) float f32x4;

__device__ __forceinline__ unsigned short f2bf(float f) {
  unsigned int u = __float_as_uint(f);
  u += 0x7fffu + ((u >> 16) & 1u);
  return (unsigned short)(u >> 16);
}

__device__ __forceinline__ void async_load16(const void* g, void* lds) {
  __builtin_amdgcn_global_load_lds(
      (const __attribute__((address_space(1))) unsigned int*)g,
      (__attribute__((address_space(3))) unsigned int*)lds, 16, 0, 0);
}

#define NXS (NN * NN / 8)        // 2M x-split threads (8 floats each)
#define NBO (2048 * 2048 / 4)    // 1M Bo threads
#define NBP (1024 * 1024 / 4)    // 256K Bp threads (Bq same)

// prep: xo[r][m]=x[r][2m+1]; xee[r][t]=x[r][4t]; xeo[r][t]=x[r][4t+2];
// Bo[c][m]=sin(pi(2m+1)(2c+1)/8192); Bp[c][t]=sin(pi*t*(2c+1)/2048);
// Bq[c][t]=sin(pi(2t+1)(2c+1)/4096)
__global__ void prep_kernel(const float* __restrict__ x,
                            unsigned short* __restrict__ xo,
                            unsigned short* __restrict__ xee,
                            unsigned short* __restrict__ xeo,
                            unsigned short* __restrict__ Bo,
                            unsigned short* __restrict__ Bp,
                            unsigned short* __restrict__ Bq) {
  int gi = blockIdx.x * blockDim.x + threadIdx.x;
  if (gi < NXS) {
    int g = gi & 511;            // 8-float group in row
    int r = gi >> 9;
    const float4* src = (const float4*)(x + (size_t)r * NN + g * 8);
    float4 v0 = src[0], v1 = src[1];    // n = 8g+0..3, 8g+4..7
    ushort4 ov;                          // odd n -> m = 4g..4g+3
    ov.x = f2bf(v0.y); ov.y = f2bf(v0.w); ov.z = f2bf(v1.y); ov.w = f2bf(v1.w);
    *(ushort4*)&xo[(size_t)r * 2048 + g * 4] = ov;
    unsigned int ee = ((unsigned)f2bf(v1.x) << 16) | f2bf(v0.x);  // t=2g,2g+1
    *(unsigned int*)&xee[(size_t)r * 1024 + g * 2] = ee;
    unsigned int eo = ((unsigned)f2bf(v1.z) << 16) | f2bf(v0.z);
    *(unsigned int*)&xeo[(size_t)r * 1024 + g * 2] = eo;
  } else if (gi < NXS + NBO) {
    int i = gi - NXS;
    int m0 = (i & 511) * 4;
    int c = i >> 9;
    unsigned int tw = 2u * (unsigned)c + 1u;
    const float sc = 3.14159265358979323846f / 8192.0f;
    ushort4 o; unsigned int ph;
    ph = ((unsigned)(2 * (m0 + 0) + 1) * tw) & 16383u; o.x = f2bf(__sinf((float)ph * sc));
    ph = ((unsigned)(2 * (m0 + 1) + 1) * tw) & 16383u; o.y = f2bf(__sinf((float)ph * sc));
    ph = ((unsigned)(2 * (m0 + 2) + 1) * tw) & 16383u; o.z = f2bf(__sinf((float)ph * sc));
    ph = ((unsigned)(2 * (m0 + 3) + 1) * tw) & 16383u; o.w = f2bf(__sinf((float)ph * sc));
    *(ushort4*)&Bo[(size_t)c * 2048 + m0] = o;
  } else if (gi < NXS + NBO + NBP) {
    int i = gi - NXS - NBO;
    int t0 = (i & 255) * 4;
    int c = i >> 8;
    unsigned int tw = 2u * (unsigned)c + 1u;
    const float sc = 3.14159265358979323846f / 2048.0f;
    ushort4 o; unsigned int ph;
    ph = ((unsigned)(t0 + 0) * tw) & 4095u; o.x = f2bf(__sinf((float)ph * sc));
    ph = ((unsigned)(t0 + 1) * tw) & 4095u; o.y = f2bf(__sinf((float)ph * sc));
    ph = ((unsigned)(t0 + 2) * tw) & 4095u; o.z = f2bf(__sinf((float)ph * sc));
    ph = ((unsigned)(t0 + 3) * tw) & 4095u; o.w = f2bf(__sinf((float)ph * sc));
    *(ushort4*)&Bp[(size_t)c * 1024 + t0] = o;
  } else {
    int i = gi - NXS - NBO - NBP;
    int t0 = (i & 255) * 4;
    int c = i >> 8;
    unsigned int tw = 2u * (unsigned)c + 1u;
    const float sc = 3.14159265358979323846f / 4096.0f;
    ushort4 o; unsigned int ph;
    ph = ((unsigned)(2 * (t0 + 0) + 1) * tw) & 8191u; o.x = f2bf(__sinf((float)ph * sc));
    ph = ((unsigned)(2 * (t0 + 1) + 1) * tw) & 8191u; o.y = f2bf(__sinf((float)ph * sc));
    ph = ((unsigned)(2 * (t0 + 2) + 1) * tw) & 8191u; o.z = f2bf(__sinf((float)ph * sc));
    ph = ((unsigned)(2 * (t0 + 3) + 1) * tw) & 8191u; o.w = f2bf(__sinf((float)ph * sc));
    *(ushort4*)&Bq[(size_t)c * 1024 + t0] = o;
  }
}

// ---- 8-phase 256x128 GEMM machinery -------------------------------------
// LDS ushort offsets: A0=0(16K) B0=16384(8K) A1=24576(16K) B1=40960(8K).
#define PH_BAR  __builtin_amdgcn_s_barrier()
#define W_LGKM0 asm volatile("s_waitcnt lgkmcnt(0)" ::: "memory")
#define W_VM2   asm volatile("s_waitcnt vmcnt(2)" ::: "memory")
#define W_VM0   asm volatile("s_waitcnt vmcnt(0)" ::: "memory")
#define PRIO1   __builtin_amdgcn_s_setprio(1)
#define PRIO0   __builtin_amdgcn_s_setprio(0)

// Stage A half-tile (128 rows x 64 k = 16KB, 2 loads/thread). Linear LDS dest;
// source chunk pre-swizzled by the chunk^(row&7) involution the reads apply.
#define STAGEA(prow0, koff, off) do {                                           \
    const unsigned short* _s =                                                  \
        A + (size_t)((prow0) + st_r) * K + (koff) + st_c;                       \
    async_load16(_s, &lds[(off) + tid * 8]);                                    \
    async_load16(_s + (size_t)64 * K, &lds[(off) + 4096 + tid * 8]);            \
  } while (0)

// Stage B half-tile (64 rows x 64 k = 8KB, 1 load/thread).
#define STAGEB(pcol0, koff, off) do {                                           \
    const unsigned short* _s =                                                  \
        Bm + (size_t)((pcol0) + st_r) * K + (koff) + st_c;                      \
    async_load16(_s, &lds[(off) + tid * 8]);                                    \
  } while (0)

// A-frags for quadrant row-half mh of buffer b (wave half wm): 8 ds_read_b128.
#define LOADA(b, mh) do {                                                       \
    const int _ab = (b) * 24576 + wm * 8192 + (mh) * 4096 + lr * 64;            \
    _Pragma("unroll") for (int _i = 0; _i < 4; ++_i) {                          \
      av[_i][0] = *(const short8*)&lds[_ab + _i * 1024 + cA0];                  \
      av[_i][1] = *(const short8*)&lds[_ab + _i * 1024 + cA1];                  \
    }                                                                           \
  } while (0)

// B-frags for quadrant col-half nh of buffer b (wave strip wn): 2 reads.
#define LOADB(SET, b, nh) do {                                                  \
    const int _bb = 16384 + (b) * 24576 + wn * 2048 + (nh) * 1024 + lr * 64;    \
    SET[0] = *(const short8*)&lds[_bb + cA0];                                   \
    SET[1] = *(const short8*)&lds[_bb + cA1];                                   \
  } while (0)

// One C-quadrant x K=64: 8 MFMA.
#define MMAQ(BS, mh, nh) do {                                                   \
    _Pragma("unroll") for (int _k = 0; _k < 2; ++_k)                            \
    _Pragma("unroll") for (int _i = 0; _i < 4; ++_i)                            \
      acc[(mh) * 4 + _i][(nh)] =                                                \
          __builtin_amdgcn_mfma_f32_16x16x32_bf16(                              \
              av[_i][_k], BS[_k], acc[(mh) * 4 + _i][(nh)], 0, 0, 0);           \
  } while (0)

__global__ __launch_bounds__(512) void gemm3_kernel(
    const unsigned short* __restrict__ xo,
    const unsigned short* __restrict__ xee,
    const unsigned short* __restrict__ xeo,
    const unsigned short* __restrict__ Bo,
    const unsigned short* __restrict__ Bp,
    const unsigned short* __restrict__ Bq,
    float* __restrict__ out) {
  __shared__ __align__(16) unsigned short lds[49152];   // 96 KiB

  // bx 0..255: U (K=2048) -> every CU gets one U block in dispatch round 1.
  const int bx = blockIdx.x;
  const unsigned short* A;
  const unsigned short* Bm;
  int K, row0, ncol0, col0;
  if (bx < 256) {
    A = xo;  Bm = Bo; K = 2048;
    row0 = (bx & 15) * 256; ncol0 = (bx >> 4) * 128; col0 = ncol0;
  } else if (bx < 384) {
    int b = bx - 256;
    A = xee; Bm = Bp; K = 1024;
    row0 = (b & 15) * 256; ncol0 = (b >> 4) * 128; col0 = 2048 + ncol0;
  } else {
    int b = bx - 384;
    A = xeo; Bm = Bq; K = 1024;
    row0 = (b & 15) * 256; ncol0 = (b >> 4) * 128; col0 = 3072 + ncol0;
  }
  const int NT = K >> 6;           // K-tiles of 64 (32 for U, 16 for P/Q)

  const int tid = threadIdx.x;
  const int lane = tid & 63;
  const int wave = tid >> 6;
  const int wm = wave >> 2;        // 0..1 : 128-row half of C
  const int wn = wave & 3;         // 0..3 : 32-col strip of C
  const int lr = lane & 15, kq = lane >> 4;
  const int st_r = tid >> 3;                         // staging row 0..63
  const int st_c = ((tid & 7) ^ (st_r & 7)) * 8;     // pre-swizzled src chunk
  const int cA0 = (kq ^ (lr & 7)) * 8;               // swizzled ds_read chunks
  const int cA1 = ((4 + kq) ^ (lr & 7)) * 8;

  f32x4 acc[8][2];
#pragma unroll
  for (int i = 0; i < 8; ++i)
#pragma unroll
    for (int j = 0; j < 2; ++j)
      acc[i][j] = (f32x4){0.f, 0.f, 0.f, 0.f};
  short8 av[4][2], bv0[2], bv1[2];

  // Prologue: tile0 A+B -> buf0 (6 loads), tile1 B -> buf1 (2 loads).
  // vmcnt(2) drains tile0, leaves B[t1] (2) in flight = steady invariant.
  STAGEA(row0,  0, 0);
  STAGEA(row0 + 128, 0, 8192);
  STAGEB(ncol0, 0, 16384);
  STAGEB(ncol0 + 64, 0, 20480);
  STAGEB(ncol0, 64, 40960);
  STAGEB(ncol0 + 64, 64, 45056);
  W_VM2; PH_BAR;

  const int NITER = NT >> 1;
  for (int it = 0; it < NITER - 1; ++it) {
    const int t64 = it << 7;       // k-offset of tile t = 2*it
    // ---- tile t (buf0) ----
    // p1: q(0,0); stage A[t+1]h0 -> buf1
    LOADA(0, 0); LOADB(bv0, 0, 0);
    STAGEA(row0, t64 + 64, 24576);
    PH_BAR; W_LGKM0; PRIO1; MMAQ(bv0, 0, 0); PRIO0; PH_BAR;
    // p2: q(0,1); stage A[t+1]h1
    LOADB(bv1, 0, 1);
    STAGEA(row0 + 128, t64 + 64, 32768);
    PH_BAR; W_LGKM0; PRIO1; MMAQ(bv1, 0, 1); PRIO0; PH_BAR;
    // p3: q(1,1); stage B[t+2]h0 -> buf0 (B0 reads ended p2)
    LOADA(0, 1);
    STAGEB(ncol0, t64 + 128, 16384);
    PH_BAR; W_LGKM0; PRIO1; MMAQ(bv1, 1, 1); PRIO0; PH_BAR;
    // p4: q(1,0); stage B[t+2]h1; counted wait -> tile t+1 resident
    STAGEB(ncol0 + 64, t64 + 128, 20480);
    PH_BAR; PRIO1; MMAQ(bv0, 1, 0); PRIO0; W_VM2; PH_BAR;
    // ---- tile t+1 (buf1) ----
    // p5: q(0,0); stage A[t+2]h0 -> buf0 (A0 reads ended p3)
    LOADA(1, 0); LOADB(bv0, 1, 0);
    STAGEA(row0, t64 + 128, 0);
    PH_BAR; W_LGKM0; PRIO1; MMAQ(bv0, 0, 0); PRIO0; PH_BAR;
    // p6: q(0,1); stage A[t+2]h1
    LOADB(bv1, 1, 1);
    STAGEA(row0 + 128, t64 + 128, 8192);
    PH_BAR; W_LGKM0; PRIO1; MMAQ(bv1, 0, 1); PRIO0; PH_BAR;
    // p7: q(1,1); stage B[t+3]h0 -> buf1 (B1 reads ended p6)
    LOADA(1, 1);
    STAGEB(ncol0, t64 + 192, 40960);
    PH_BAR; W_LGKM0; PRIO1; MMAQ(bv1, 1, 1); PRIO0; PH_BAR;
    // p8: q(1,0); stage B[t+3]h1; counted wait -> tile t+2 resident
    STAGEB(ncol0 + 64, t64 + 192, 45056);
    PH_BAR; PRIO1; MMAQ(bv0, 1, 0); PRIO0; W_VM2; PH_BAR;
  }

  // Peeled last iteration (tiles NT-2 -> buf0, NT-1 -> buf1): only A[NT-1]
  // left to stage; drain to vmcnt(0) at p4; p5-p8 barrier-free.
  {
    const int t64 = (NT - 2) << 6;
    LOADA(0, 0); LOADB(bv0, 0, 0);
    STAGEA(row0, t64 + 64, 24576);
    PH_BAR; W_LGKM0; PRIO1; MMAQ(bv0, 0, 0); PRIO0; PH_BAR;
    LOADB(bv1, 0, 1);
    STAGEA(row0 + 128, t64 + 64, 32768);
    PH_BAR; W_LGKM0; PRIO1; MMAQ(bv1, 0, 1); PRIO0; PH_BAR;
    LOADA(0, 1);
    PH_BAR; W_LGKM0; PRIO1; MMAQ(bv1, 1, 1); PRIO0; PH_BAR;
    PRIO1; MMAQ(bv0, 1, 0); PRIO0; W_VM0; PH_BAR;
    // tile NT-1 (buf1): no more staging, no barriers needed
    LOADA(1, 0); LOADB(bv0, 1, 0);
    W_LGKM0; PRIO1; MMAQ(bv0, 0, 0); PRIO0;
    LOADB(bv1, 1, 1);
    W_LGKM0; PRIO1; MMAQ(bv1, 0, 1); PRIO0;
    LOADA(1, 1);
    W_LGKM0; PRIO1; MMAQ(bv1, 1, 1); MMAQ(bv0, 1, 0); PRIO0;
  }

  // C/D layout: col=lane&15, row=quad*4+reg
#pragma unroll
  for (int i = 0; i < 8; ++i)
#pragma unroll
    for (int j = 0; j < 2; ++j)
#pragma unroll
      for (int r = 0; r < 4; ++r) {
        int row = row0 + wm * 128 + i * 16 + kq * 4 + r;
        int col = col0 + wn * 32 + j * 16 + lr;
        out[(size_t)row * NN + col] = acc[i][j][r];
      }
}

// In-place combine, both fold levels. Row layout on entry:
// [0:2048)=u, [2048:3072)=p, [3072:4096)=q.
// v[k']=p+q, v[2047-k']=q-p (k'<1024); y[k]=v[k]+u[k], y[4095-k]=u[k]-v[k].
__global__ void combine_kernel(float* __restrict__ out) {
  int t = blockIdx.x * blockDim.x + threadIdx.x;   // 4096 rows * 128 threads
  int r = t >> 7;
  int k0 = (t & 127) * 4;                          // [0,512)
  float* row = out + (size_t)r * NN;
  float U0[4], U1[4], U2[4], U3[4], P0[4], P1[4], Q0[4], Q1[4];
  *(float4*)U0 = *(float4*)&row[k0];          // u[k0+e]
  *(float4*)U1 = *(float4*)&row[1020 - k0];   // u[1023-k'] rev
  *(float4*)U2 = *(float4*)&row[1024 + k0];   // u[1024+k0+e]
  *(float4*)U3 = *(float4*)&row[2044 - k0];   // u[2047-k'] rev
  *(float4*)P0 = *(float4*)&row[2048 + k0];   // p[k0+e]
  *(float4*)P1 = *(float4*)&row[3068 - k0];   // p[1023-k'] rev
  *(float4*)Q0 = *(float4*)&row[3072 + k0];   // q[k0+e]
  *(float4*)Q1 = *(float4*)&row[4092 - k0];   // q[1023-k'] rev
  float YA[4], YB[4], YC[4], YD[4], YE[4], YF[4], YG[4], YH[4];
#pragma unroll
  for (int e = 0; e < 4; ++e) {
    float v1 = P0[e] + Q0[e];        // v[k']
    float v2 = Q0[e] - P0[e];        // v[2047-k']
    float um = U3[3 - e];            // u[2047-k']
    YA[e] = v1 + U0[e];              // y[k']
    YB[3 - e] = U0[e] - v1;          // y[4095-k']
    YC[3 - e] = v2 + um;             // y[2047-k']
    YD[e] = um - v2;                 // y[2048+k']
    float pm = P1[3 - e], qm = Q1[3 - e];
    float w1 = pm + qm;              // v[1023-k']
    float w2 = qm - pm;              // v[1024+k']
    float umm = U1[3 - e];           // u[1023-k']
    YE[3 - e] = w1 + umm;            // y[1023-k']
    YF[e] = umm - w1;                // y[3072+k']
    YG[e] = w2 + U2[e];              // y[1024+k']
    YH[3 - e] = U2[e] - w2;          // y[3071-k']
  }
  *(float4*)&row[k0] = *(float4*)YA;
  *(float4*)&row[4092 - k0] = *(float4*)YB;
  *(float4*)&row[2044 - k0] = *(float4*)YC;
  *(float4*)&row[2048 + k0] = *(float4*)YD;
  *(float4*)&row[1020 - k0] = *(float4*)YE;
  *(float4*)&row[3072 + k0] = *(float4*)YF;
  *(float4*)&row[1024 + k0] = *(float4*)YG;
  *(float4*)&row[3068 - k0] = *(float4*)YH;
}

extern "C" void kernel_launch(void* const* d_in, const int* in_sizes, int n_in,
                              void* d_out, int out_size, void* d_ws, size_t ws_size,
                              hipStream_t stream) {
  const float* x = (const float*)d_in[0];
  float* out = (float*)d_out;
  unsigned short* xo  = (unsigned short*)d_ws;            // 16 MB
  unsigned short* xee = xo + (size_t)NN * 2048;           // 8 MB
  unsigned short* xeo = xee + (size_t)NN * 1024;          // 8 MB
  unsigned short* Bo  = xeo + (size_t)NN * 1024;          // 8 MB
  unsigned short* Bp  = Bo + (size_t)2048 * 2048;         // 2 MB
  unsigned short* Bq  = Bp + (size_t)1024 * 1024;         // 2 MB -> 44 MB total

  int prep_threads = NXS + NBO + 2 * NBP;
  prep_kernel<<<prep_threads / 256, 256, 0, stream>>>(x, xo, xee, xeo, Bo, Bp, Bq);

  gemm3_kernel<<<512, 512, 0, stream>>>(xo, xee, xeo, Bo, Bp, Bq, out);

  combine_kernel<<<NN * 128 / 256, 256, 0, stream>>>(out);
}

// Round 7
// 99.076 us; speedup vs baseline: 2.3294x; 1.0220x over previous
//
#include <hip/hip_runtime.h>
#include <stdint.h>

// IDXST(4096x4096): y[r][k] = sum_n x[r][n] sin(pi*n*(2k+1)/8192).
// R12: R11 (balanced 256x128 tiles, 512 blocks, 8-phase) + TWO BLOCKS PER CU.
// R11's phase = MFMA 310 + LDS-read ~480 cyc SERIALIZED by the barrier
// lockstep (780 cyc measured); neither pipe saturated. Cross-block TLP is the
// proven overlap mechanism (m114): two unsynced blocks per CU let one block's
// LDS window hide under the other's MFMA window.
// LDS 96->80KB: A double-buffered (2x16KB x2), B SINGLE-buffered (16KB).
//   B[t] last read p2 (sealed by p2 trailing barrier) -> stage B[t+1] at p3
//   -> vmcnt(0) at p4 + barrier -> read at p5. Every staged load gets >=1
//   full phase before its drain (~700cyc > L2 latency). 2x80KB = 160KB exact.
// 16 waves/CU (4/SIMD). Dispatch: all 512 blocks co-resident at t=0;
// breadth-first round1 = U (one per CU), round2 = P/Q -> 134+67 MF pairing.
// ws (44 MB): xo 16 | xee 8 | xeo 8 | Bo 8 | Bp 2 | Bq 2.

#define NN 4096

typedef __attribute__((ext_vector_type(8))) short short8;
typedef __attribute__((ext_vector_type(4))) float f32x4;

__device__ __forceinline__ unsigned short f2bf(float f) {
  unsigned int u = __float_as_uint(f);
  u += 0x7fffu + ((u >> 16) & 1u);
  return (unsigned short)(u >> 16);
}

__device__ __forceinline__ void async_load16(const void* g, void* lds) {
  __builtin_amdgcn_global_load_lds(
      (const __attribute__((address_space(1))) unsigned int*)g,
      (__attribute__((address_space(3))) unsigned int*)lds, 16, 0, 0);
}

#define NXS (NN * NN / 8)        // 2M x-split threads (8 floats each)
#define NBO (2048 * 2048 / 4)    // 1M Bo threads
#define NBP (1024 * 1024 / 4)    // 256K Bp threads (Bq same)

// prep: xo[r][m]=x[r][2m+1]; xee[r][t]=x[r][4t]; xeo[r][t]=x[r][4t+2];
// Bo[c][m]=sin(pi(2m+1)(2c+1)/8192); Bp[c][t]=sin(pi*t*(2c+1)/2048);
// Bq[c][t]=sin(pi(2t+1)(2c+1)/4096)
__global__ void prep_kernel(const float* __restrict__ x,
                            unsigned short* __restrict__ xo,
                            unsigned short* __restrict__ xee,
                            unsigned short* __restrict__ xeo,
                            unsigned short* __restrict__ Bo,
                            unsigned short* __restrict__ Bp,
                            unsigned short* __restrict__ Bq) {
  int gi = blockIdx.x * blockDim.x + threadIdx.x;
  if (gi < NXS) {
    int g = gi & 511;            // 8-float group in row
    int r = gi >> 9;
    const float4* src = (const float4*)(x + (size_t)r * NN + g * 8);
    float4 v0 = src[0], v1 = src[1];    // n = 8g+0..3, 8g+4..7
    ushort4 ov;                          // odd n -> m = 4g..4g+3
    ov.x = f2bf(v0.y); ov.y = f2bf(v0.w); ov.z = f2bf(v1.y); ov.w = f2bf(v1.w);
    *(ushort4*)&xo[(size_t)r * 2048 + g * 4] = ov;
    unsigned int ee = ((unsigned)f2bf(v1.x) << 16) | f2bf(v0.x);  // t=2g,2g+1
    *(unsigned int*)&xee[(size_t)r * 1024 + g * 2] = ee;
    unsigned int eo = ((unsigned)f2bf(v1.z) << 16) | f2bf(v0.z);
    *(unsigned int*)&xeo[(size_t)r * 1024 + g * 2] = eo;
  } else if (gi < NXS + NBO) {
    int i = gi - NXS;
    int m0 = (i & 511) * 4;
    int c = i >> 9;
    unsigned int tw = 2u * (unsigned)c + 1u;
    const float sc = 3.14159265358979323846f / 8192.0f;
    ushort4 o; unsigned int ph;
    ph = ((unsigned)(2 * (m0 + 0) + 1) * tw) & 16383u; o.x = f2bf(__sinf((float)ph * sc));
    ph = ((unsigned)(2 * (m0 + 1) + 1) * tw) & 16383u; o.y = f2bf(__sinf((float)ph * sc));
    ph = ((unsigned)(2 * (m0 + 2) + 1) * tw) & 16383u; o.z = f2bf(__sinf((float)ph * sc));
    ph = ((unsigned)(2 * (m0 + 3) + 1) * tw) & 16383u; o.w = f2bf(__sinf((float)ph * sc));
    *(ushort4*)&Bo[(size_t)c * 2048 + m0] = o;
  } else if (gi < NXS + NBO + NBP) {
    int i = gi - NXS - NBO;
    int t0 = (i & 255) * 4;
    int c = i >> 8;
    unsigned int tw = 2u * (unsigned)c + 1u;
    const float sc = 3.14159265358979323846f / 2048.0f;
    ushort4 o; unsigned int ph;
    ph = ((unsigned)(t0 + 0) * tw) & 4095u; o.x = f2bf(__sinf((float)ph * sc));
    ph = ((unsigned)(t0 + 1) * tw) & 4095u; o.y = f2bf(__sinf((float)ph * sc));
    ph = ((unsigned)(t0 + 2) * tw) & 4095u; o.z = f2bf(__sinf((float)ph * sc));
    ph = ((unsigned)(t0 + 3) * tw) & 4095u; o.w = f2bf(__sinf((float)ph * sc));
    *(ushort4*)&Bp[(size_t)c * 1024 + t0] = o;
  } else {
    int i = gi - NXS - NBO - NBP;
    int t0 = (i & 255) * 4;
    int c = i >> 8;
    unsigned int tw = 2u * (unsigned)c + 1u;
    const float sc = 3.14159265358979323846f / 4096.0f;
    ushort4 o; unsigned int ph;
    ph = ((unsigned)(2 * (t0 + 0) + 1) * tw) & 8191u; o.x = f2bf(__sinf((float)ph * sc));
    ph = ((unsigned)(2 * (t0 + 1) + 1) * tw) & 8191u; o.y = f2bf(__sinf((float)ph * sc));
    ph = ((unsigned)(2 * (t0 + 2) + 1) * tw) & 8191u; o.z = f2bf(__sinf((float)ph * sc));
    ph = ((unsigned)(2 * (t0 + 3) + 1) * tw) & 8191u; o.w = f2bf(__sinf((float)ph * sc));
    *(ushort4*)&Bq[(size_t)c * 1024 + t0] = o;
  }
}

// ---- 8-phase 256x128 GEMM, 80KB LDS ------------------------------------
// LDS ushort offsets: A buf0 [0,16384), A buf1 [16384,32768), B [32768,40960).
#define PH_BAR  __builtin_amdgcn_s_barrier()
#define W_LGKM0 asm volatile("s_waitcnt lgkmcnt(0)" ::: "memory")
#define W_VM0   asm volatile("s_waitcnt vmcnt(0)" ::: "memory")
#define PRIO1   __builtin_amdgcn_s_setprio(1)
#define PRIO0   __builtin_amdgcn_s_setprio(0)

// Stage A half-tile (128 rows x 64 k = 16KB, 2 loads/thread). Linear LDS dest;
// source chunk pre-swizzled by the chunk^(row&7) involution the reads apply.
#define STAGEA(prow0, koff, off) do {                                           \
    const unsigned short* _s =                                                  \
        A + (size_t)((prow0) + st_r) * K + (koff) + st_c;                       \
    async_load16(_s, &lds[(off) + tid * 8]);                                    \
    async_load16(_s + (size_t)64 * K, &lds[(off) + 4096 + tid * 8]);            \
  } while (0)

// Stage B half-tile (64 rows x 64 k = 8KB, 1 load/thread).
#define STAGEB(pcol0, koff, off) do {                                           \
    const unsigned short* _s =                                                  \
        Bm + (size_t)((pcol0) + st_r) * K + (koff) + st_c;                      \
    async_load16(_s, &lds[(off) + tid * 8]);                                    \
  } while (0)

// A-frags for quadrant row-half mh of buffer b (wave half wm): 8 ds_read_b128.
#define LOADA(b, mh) do {                                                       \
    const int _ab = (b) * 16384 + wm * 8192 + (mh) * 4096 + lr * 64;            \
    _Pragma("unroll") for (int _i = 0; _i < 4; ++_i) {                          \
      av[_i][0] = *(const short8*)&lds[_ab + _i * 1024 + cA0];                  \
      av[_i][1] = *(const short8*)&lds[_ab + _i * 1024 + cA1];                  \
    }                                                                           \
  } while (0)

// B-frags for quadrant col-half nh (single B buffer, wave strip wn): 2 reads.
#define LOADB(SET, nh) do {                                                     \
    const int _bb = 32768 + wn * 2048 + (nh) * 1024 + lr * 64;                  \
    SET[0] = *(const short8*)&lds[_bb + cA0];                                   \
    SET[1] = *(const short8*)&lds[_bb + cA1];                                   \
  } while (0)

// One C-quadrant x K=64: 8 MFMA.
#define MMAQ(BS, mh, nh) do {                                                   \
    _Pragma("unroll") for (int _k = 0; _k < 2; ++_k)                            \
    _Pragma("unroll") for (int _i = 0; _i < 4; ++_i)                            \
      acc[(mh) * 4 + _i][(nh)] =                                                \
          __builtin_amdgcn_mfma_f32_16x16x32_bf16(                              \
              av[_i][_k], BS[_k], acc[(mh) * 4 + _i][(nh)], 0, 0, 0);           \
  } while (0)

__global__ __launch_bounds__(512) void gemm3_kernel(
    const unsigned short* __restrict__ xo,
    const unsigned short* __restrict__ xee,
    const unsigned short* __restrict__ xeo,
    const unsigned short* __restrict__ Bo,
    const unsigned short* __restrict__ Bp,
    const unsigned short* __restrict__ Bq,
    float* __restrict__ out) {
  __shared__ __align__(16) unsigned short lds[40960];   // 80 KiB -> 2 blk/CU

  // bx 0..255: U (K=2048) -> breadth-first round 1 puts one U on every CU.
  const int bx = blockIdx.x;
  const unsigned short* A;
  const unsigned short* Bm;
  int K, row0, ncol0, col0;
  if (bx < 256) {
    A = xo;  Bm = Bo; K = 2048;
    row0 = (bx & 15) * 256; ncol0 = (bx >> 4) * 128; col0 = ncol0;
  } else if (bx < 384) {
    int b = bx - 256;
    A = xee; Bm = Bp; K = 1024;
    row0 = (b & 15) * 256; ncol0 = (b >> 4) * 128; col0 = 2048 + ncol0;
  } else {
    int b = bx - 384;
    A = xeo; Bm = Bq; K = 1024;
    row0 = (b & 15) * 256; ncol0 = (b >> 4) * 128; col0 = 3072 + ncol0;
  }
  const int NT = K >> 6;           // K-tiles of 64 (32 for U, 16 for P/Q)

  const int tid = threadIdx.x;
  const int lane = tid & 63;
  const int wave = tid >> 6;
  const int wm = wave >> 2;        // 0..1 : 128-row half of C
  const int wn = wave & 3;         // 0..3 : 32-col strip of C
  const int lr = lane & 15, kq = lane >> 4;
  const int st_r = tid >> 3;                         // staging row 0..63
  const int st_c = ((tid & 7) ^ (st_r & 7)) * 8;     // pre-swizzled src chunk
  const int cA0 = (kq ^ (lr & 7)) * 8;               // swizzled ds_read chunks
  const int cA1 = ((4 + kq) ^ (lr & 7)) * 8;

  f32x4 acc[8][2];
#pragma unroll
  for (int i = 0; i < 8; ++i)
#pragma unroll
    for (int j = 0; j < 2; ++j)
      acc[i][j] = (f32x4){0.f, 0.f, 0.f, 0.f};
  short8 av[4][2], bv0[2], bv1[2];

  // Prologue: tile0 A -> buf0, B[0] -> B region; full drain.
  STAGEA(row0,       0, 0);
  STAGEA(row0 + 128, 0, 8192);
  STAGEB(ncol0,      0, 32768);
  STAGEB(ncol0 + 64, 0, 36864);
  W_VM0; PH_BAR;

  const int NITER = NT >> 1;
  for (int it = 0; it < NITER - 1; ++it) {
    const int t64 = it << 7;       // k-offset of tile t = 2*it
    // ---- tile t (buf0); stage A[t+1]->buf1, B[t+1] ----
    // p1: q(0,0); stage A[t+1]h0
    LOADA(0, 0); LOADB(bv0, 0);
    STAGEA(row0, t64 + 64, 16384);
    PH_BAR; W_LGKM0; PRIO1; MMAQ(bv0, 0, 0); PRIO0; PH_BAR;
    // p2: q(0,1); stage A[t+1]h1  (last B[t] read is here)
    LOADB(bv1, 1);
    STAGEA(row0 + 128, t64 + 64, 24576);
    PH_BAR; W_LGKM0; PRIO1; MMAQ(bv1, 0, 1); PRIO0; PH_BAR;
    // p3: q(1,1); stage B[t+1] (B reads sealed by p2 trailing barrier)
    LOADA(0, 1);
    STAGEB(ncol0,      t64 + 64, 32768);
    STAGEB(ncol0 + 64, t64 + 64, 36864);
    PH_BAR; W_LGKM0; PRIO1; MMAQ(bv1, 1, 1); PRIO0; PH_BAR;
    // p4: q(1,0); drain tile t+1 (A 4 + B 2 loads), barrier
    PRIO1; MMAQ(bv0, 1, 0); PRIO0; W_VM0; PH_BAR;
    // ---- tile t+1 (buf1); stage A[t+2]->buf0, B[t+2] ----
    // p5: q(0,0); stage A[t+2]h0
    LOADA(1, 0); LOADB(bv0, 0);
    STAGEA(row0, t64 + 128, 0);
    PH_BAR; W_LGKM0; PRIO1; MMAQ(bv0, 0, 0); PRIO0; PH_BAR;
    // p6: q(0,1); stage A[t+2]h1
    LOADB(bv1, 1);
    STAGEA(row0 + 128, t64 + 128, 8192);
    PH_BAR; W_LGKM0; PRIO1; MMAQ(bv1, 0, 1); PRIO0; PH_BAR;
    // p7: q(1,1); stage B[t+2]
    LOADA(1, 1);
    STAGEB(ncol0,      t64 + 128, 32768);
    STAGEB(ncol0 + 64, t64 + 128, 36864);
    PH_BAR; W_LGKM0; PRIO1; MMAQ(bv1, 1, 1); PRIO0; PH_BAR;
    // p8: q(1,0); drain tile t+2, barrier
    PRIO1; MMAQ(bv0, 1, 0); PRIO0; W_VM0; PH_BAR;
  }

  // Peeled last pair (tiles NT-2 -> buf0, NT-1 -> buf1): stage only A[NT-1]
  // and B[NT-1] during the first tile; tail barrier-free.
  {
    const int t64 = (NT - 2) << 6;
    LOADA(0, 0); LOADB(bv0, 0);
    STAGEA(row0, t64 + 64, 16384);
    PH_BAR; W_LGKM0; PRIO1; MMAQ(bv0, 0, 0); PRIO0; PH_BAR;
    LOADB(bv1, 1);
    STAGEA(row0 + 128, t64 + 64, 24576);
    PH_BAR; W_LGKM0; PRIO1; MMAQ(bv1, 0, 1); PRIO0; PH_BAR;
    LOADA(0, 1);
    STAGEB(ncol0,      t64 + 64, 32768);
    STAGEB(ncol0 + 64, t64 + 64, 36864);
    PH_BAR; W_LGKM0; PRIO1; MMAQ(bv1, 1, 1); PRIO0; PH_BAR;
    PRIO1; MMAQ(bv0, 1, 0); PRIO0; W_VM0; PH_BAR;
    // tile NT-1 (buf1): no staging, no cross-wave hazards -> no barriers
    LOADA(1, 0); LOADB(bv0, 0);
    W_LGKM0; PRIO1; MMAQ(bv0, 0, 0); PRIO0;
    LOADB(bv1, 1);
    W_LGKM0; PRIO1; MMAQ(bv1, 0, 1); PRIO0;
    LOADA(1, 1);
    W_LGKM0; PRIO1; MMAQ(bv1, 1, 1); MMAQ(bv0, 1, 0); PRIO0;
  }

  // C/D layout: col=lane&15, row=quad*4+reg
#pragma unroll
  for (int i = 0; i < 8; ++i)
#pragma unroll
    for (int j = 0; j < 2; ++j)
#pragma unroll
      for (int r = 0; r < 4; ++r) {
        int row = row0 + wm * 128 + i * 16 + kq * 4 + r;
        int col = col0 + wn * 32 + j * 16 + lr;
        out[(size_t)row * NN + col] = acc[i][j][r];
      }
}

// In-place combine, both fold levels. Row layout on entry:
// [0:2048)=u, [2048:3072)=p, [3072:4096)=q.
// v[k']=p+q, v[2047-k']=q-p (k'<1024); y[k]=v[k]+u[k], y[4095-k]=u[k]-v[k].
__global__ void combine_kernel(float* __restrict__ out) {
  int t = blockIdx.x * blockDim.x + threadIdx.x;   // 4096 rows * 128 threads
  int r = t >> 7;
  int k0 = (t & 127) * 4;                          // [0,512)
  float* row = out + (size_t)r * NN;
  float U0[4], U1[4], U2[4], U3[4], P0[4], P1[4], Q0[4], Q1[4];
  *(float4*)U0 = *(float4*)&row[k0];          // u[k0+e]
  *(float4*)U1 = *(float4*)&row[1020 - k0];   // u[1023-k'] rev
  *(float4*)U2 = *(float4*)&row[1024 + k0];   // u[1024+k0+e]
  *(float4*)U3 = *(float4*)&row[2044 - k0];   // u[2047-k'] rev
  *(float4*)P0 = *(float4*)&row[2048 + k0];   // p[k0+e]
  *(float4*)P1 = *(float4*)&row[3068 - k0];   // p[1023-k'] rev
  *(float4*)Q0 = *(float4*)&row[3072 + k0];   // q[k0+e]
  *(float4*)Q1 = *(float4*)&row[4092 - k0];   // q[1023-k'] rev
  float YA[4], YB[4], YC[4], YD[4], YE[4], YF[4], YG[4], YH[4];
#pragma unroll
  for (int e = 0; e < 4; ++e) {
    float v1 = P0[e] + Q0[e];        // v[k']
    float v2 = Q0[e] - P0[e];        // v[2047-k']
    float um = U3[3 - e];            // u[2047-k']
    YA[e] = v1 + U0[e];              // y[k']
    YB[3 - e] = U0[e] - v1;          // y[4095-k']
    YC[3 - e] = v2 + um;             // y[2047-k']
    YD[e] = um - v2;                 // y[2048+k']
    float pm = P1[3 - e], qm = Q1[3 - e];
    float w1 = pm + qm;              // v[1023-k']
    float w2 = qm - pm;              // v[1024+k']
    float umm = U1[3 - e];           // u[1023-k']
    YE[3 - e] = w1 + umm;            // y[1023-k']
    YF[e] = umm - w1;                // y[3072+k']
    YG[e] = w2 + U2[e];              // y[1024+k']
    YH[3 - e] = U2[e] - w2;          // y[3071-k']
  }
  *(float4*)&row[k0] = *(float4*)YA;
  *(float4*)&row[4092 - k0] = *(float4*)YB;
  *(float4*)&row[2044 - k0] = *(float4*)YC;
  *(float4*)&row[2048 + k0] = *(float4*)YD;
  *(float4*)&row[1020 - k0] = *(float4*)YE;
  *(float4*)&row[3072 + k0] = *(float4*)YF;
  *(float4*)&row[1024 + k0] = *(float4*)YG;
  *(float4*)&row[3068 - k0] = *(float4*)YH;
}

extern "C" void kernel_launch(void* const* d_in, const int* in_sizes, int n_in,
                              void* d_out, int out_size, void* d_ws, size_t ws_size,
                              hipStream_t stream) {
  const float* x = (const float*)d_in[0];
  float* out = (float*)d_out;
  unsigned short* xo  = (unsigned short*)d_ws;            // 16 MB
  unsigned short* xee = xo + (size_t)NN * 2048;           // 8 MB
  unsigned short* xeo = xee + (size_t)NN * 1024;          // 8 MB
  unsigned short* Bo  = xeo + (size_t)NN * 1024;          // 8 MB
  unsigned short* Bp  = Bo + (size_t)2048 * 2048;         // 2 MB
  unsigned short* Bq  = Bp + (size_t)1024 * 1024;         // 2 MB -> 44 MB total

  int prep_threads = NXS + NBO + 2 * NBP;
  prep_kernel<<<prep_threads / 256, 256, 0, stream>>>(x, xo, xee, xeo, Bo, Bp, Bq);

  gemm3_kernel<<<512, 512, 0, stream>>>(xo, xee, xeo, Bo, Bp, Bq, out);

  combine_kernel<<<NN * 128 / 256, 256, 0, stream>>>(out);
}

// Round 8
// 97.629 us; speedup vs baseline: 2.3640x; 1.0148x over previous
//
#include <hip/hip_runtime.h>
#include <stdint.h>

// IDXST(4096x4096): y[r][k] = sum_n x[r][n] sin(pi*n*(2k+1)/8192).
// R13: R12 (balanced 256x128 tiles, 512 blocks, 8-phase, 80KB LDS) with the
// wave grid changed (2Mx4N) -> (4Mx2N): per-wave output 64x64 instead of
// 128x32. LDS-read amplification = (gn*M + gm*N)*128B: (2,4)=160KB ->
// (4,2)=128KB per K-tile (-20%), the dominant term of the measured 780cyc
// phase (MFMA 258 + LDS-read ~470 + stage ~80, serialized). Same MFMA count,
// same staging, same schedule/hazard structure; only fragment indexing and
// per-phase read pattern (16 vs 20 b128/wave/K-tile) change.
// R12 post-mortem: 2 blk/CU at 2x80KB never became resident (occupancy
// unchanged) — LDS reservation/granularity; dropped that line.
// ws (44 MB): xo 16 | xee 8 | xeo 8 | Bo 8 | Bp 2 | Bq 2.

#define NN 4096

typedef __attribute__((ext_vector_type(8))) short short8;
typedef __attribute__((ext_vector_type(4))) float f32x4;

__device__ __forceinline__ unsigned short f2bf(float f) {
  unsigned int u = __float_as_uint(f);
  u += 0x7fffu + ((u >> 16) & 1u);
  return (unsigned short)(u >> 16);
}

__device__ __forceinline__ void async_load16(const void* g, void* lds) {
  __builtin_amdgcn_global_load_lds(
      (const __attribute__((address_space(1))) unsigned int*)g,
      (__attribute__((address_space(3))) unsigned int*)lds, 16, 0, 0);
}

#define NXS (NN * NN / 8)        // 2M x-split threads (8 floats each)
#define NBO (2048 * 2048 / 4)    // 1M Bo threads
#define NBP (1024 * 1024 / 4)    // 256K Bp threads (Bq same)

// prep: xo[r][m]=x[r][2m+1]; xee[r][t]=x[r][4t]; xeo[r][t]=x[r][4t+2];
// Bo[c][m]=sin(pi(2m+1)(2c+1)/8192); Bp[c][t]=sin(pi*t*(2c+1)/2048);
// Bq[c][t]=sin(pi(2t+1)(2c+1)/4096)
__global__ void prep_kernel(const float* __restrict__ x,
                            unsigned short* __restrict__ xo,
                            unsigned short* __restrict__ xee,
                            unsigned short* __restrict__ xeo,
                            unsigned short* __restrict__ Bo,
                            unsigned short* __restrict__ Bp,
                            unsigned short* __restrict__ Bq) {
  int gi = blockIdx.x * blockDim.x + threadIdx.x;
  if (gi < NXS) {
    int g = gi & 511;            // 8-float group in row
    int r = gi >> 9;
    const float4* src = (const float4*)(x + (size_t)r * NN + g * 8);
    float4 v0 = src[0], v1 = src[1];    // n = 8g+0..3, 8g+4..7
    ushort4 ov;                          // odd n -> m = 4g..4g+3
    ov.x = f2bf(v0.y); ov.y = f2bf(v0.w); ov.z = f2bf(v1.y); ov.w = f2bf(v1.w);
    *(ushort4*)&xo[(size_t)r * 2048 + g * 4] = ov;
    unsigned int ee = ((unsigned)f2bf(v1.x) << 16) | f2bf(v0.x);  // t=2g,2g+1
    *(unsigned int*)&xee[(size_t)r * 1024 + g * 2] = ee;
    unsigned int eo = ((unsigned)f2bf(v1.z) << 16) | f2bf(v0.z);
    *(unsigned int*)&xeo[(size_t)r * 1024 + g * 2] = eo;
  } else if (gi < NXS + NBO) {
    int i = gi - NXS;
    int m0 = (i & 511) * 4;
    int c = i >> 9;
    unsigned int tw = 2u * (unsigned)c + 1u;
    const float sc = 3.14159265358979323846f / 8192.0f;
    ushort4 o; unsigned int ph;
    ph = ((unsigned)(2 * (m0 + 0) + 1) * tw) & 16383u; o.x = f2bf(__sinf((float)ph * sc));
    ph = ((unsigned)(2 * (m0 + 1) + 1) * tw) & 16383u; o.y = f2bf(__sinf((float)ph * sc));
    ph = ((unsigned)(2 * (m0 + 2) + 1) * tw) & 16383u; o.z = f2bf(__sinf((float)ph * sc));
    ph = ((unsigned)(2 * (m0 + 3) + 1) * tw) & 16383u; o.w = f2bf(__sinf((float)ph * sc));
    *(ushort4*)&Bo[(size_t)c * 2048 + m0] = o;
  } else if (gi < NXS + NBO + NBP) {
    int i = gi - NXS - NBO;
    int t0 = (i & 255) * 4;
    int c = i >> 8;
    unsigned int tw = 2u * (unsigned)c + 1u;
    const float sc = 3.14159265358979323846f / 2048.0f;
    ushort4 o; unsigned int ph;
    ph = ((unsigned)(t0 + 0) * tw) & 4095u; o.x = f2bf(__sinf((float)ph * sc));
    ph = ((unsigned)(t0 + 1) * tw) & 4095u; o.y = f2bf(__sinf((float)ph * sc));
    ph = ((unsigned)(t0 + 2) * tw) & 4095u; o.z = f2bf(__sinf((float)ph * sc));
    ph = ((unsigned)(t0 + 3) * tw) & 4095u; o.w = f2bf(__sinf((float)ph * sc));
    *(ushort4*)&Bp[(size_t)c * 1024 + t0] = o;
  } else {
    int i = gi - NXS - NBO - NBP;
    int t0 = (i & 255) * 4;
    int c = i >> 8;
    unsigned int tw = 2u * (unsigned)c + 1u;
    const float sc = 3.14159265358979323846f / 4096.0f;
    ushort4 o; unsigned int ph;
    ph = ((unsigned)(2 * (t0 + 0) + 1) * tw) & 8191u; o.x = f2bf(__sinf((float)ph * sc));
    ph = ((unsigned)(2 * (t0 + 1) + 1) * tw) & 8191u; o.y = f2bf(__sinf((float)ph * sc));
    ph = ((unsigned)(2 * (t0 + 2) + 1) * tw) & 8191u; o.z = f2bf(__sinf((float)ph * sc));
    ph = ((unsigned)(2 * (t0 + 3) + 1) * tw) & 8191u; o.w = f2bf(__sinf((float)ph * sc));
    *(ushort4*)&Bq[(size_t)c * 1024 + t0] = o;
  }
}

// ---- 8-phase 256x128 GEMM, 80KB LDS, wave grid 4Mx2N --------------------
// LDS ushort offsets: A buf0 [0,16384), A buf1 [16384,32768), B [32768,40960).
// A row r of buffer b at b*16384 + r*64; B col c at 32768 + c*64.
#define PH_BAR  __builtin_amdgcn_s_barrier()
#define W_LGKM0 asm volatile("s_waitcnt lgkmcnt(0)" ::: "memory")
#define W_VM0   asm volatile("s_waitcnt vmcnt(0)" ::: "memory")
#define PRIO1   __builtin_amdgcn_s_setprio(1)
#define PRIO0   __builtin_amdgcn_s_setprio(0)

// Stage A half-tile (128 rows x 64 k = 16KB, 2 loads/thread). Linear LDS dest;
// source chunk pre-swizzled by the chunk^(row&7) involution the reads apply.
#define STAGEA(prow0, koff, off) do {                                           \
    const unsigned short* _s =                                                  \
        A + (size_t)((prow0) + st_r) * K + (koff) + st_c;                       \
    async_load16(_s, &lds[(off) + tid * 8]);                                    \
    async_load16(_s + (size_t)64 * K, &lds[(off) + 4096 + tid * 8]);            \
  } while (0)

// Stage B half-tile (64 rows x 64 k = 8KB, 1 load/thread).
#define STAGEB(pcol0, koff, off) do {                                           \
    const unsigned short* _s =                                                  \
        Bm + (size_t)((pcol0) + st_r) * K + (koff) + st_c;                      \
    async_load16(_s, &lds[(off) + tid * 8]);                                    \
  } while (0)

// A-frags for row-half mh (32 rows = frags mh*2, mh*2+1) of buffer b.
// Wave's rows: wm*64 + mh*32 + i*16 + lr. 4 ds_read_b128.
#define LOADA(b, mh) do {                                                       \
    const int _ab = (b) * 16384 + wm * 4096 + (mh) * 2048 + lr * 64;            \
    _Pragma("unroll") for (int _i = 0; _i < 2; ++_i) {                          \
      av[(mh) * 2 + _i][0] = *(const short8*)&lds[_ab + _i * 1024 + cA0];       \
      av[(mh) * 2 + _i][1] = *(const short8*)&lds[_ab + _i * 1024 + cA1];       \
    }                                                                           \
  } while (0)

// B-frags for col-half nh (32 cols) into SET[2][2]. Wave's cols:
// wn*64 + nh*32 + j*16 + lr. 4 ds_read_b128.
#define LOADB(SET, nh) do {                                                     \
    const int _bb = 32768 + wn * 4096 + (nh) * 2048 + lr * 64;                  \
    _Pragma("unroll") for (int _j = 0; _j < 2; ++_j) {                          \
      SET[_j][0] = *(const short8*)&lds[_bb + _j * 1024 + cA0];                 \
      SET[_j][1] = *(const short8*)&lds[_bb + _j * 1024 + cA1];                 \
    }                                                                           \
  } while (0)

// One 32x32 C-quadrant x K=64: 8 MFMA.
#define MMAQ(BS, mh, nh) do {                                                   \
    _Pragma("unroll") for (int _k = 0; _k < 2; ++_k)                            \
    _Pragma("unroll") for (int _i = 0; _i < 2; ++_i)                            \
    _Pragma("unroll") for (int _j = 0; _j < 2; ++_j)                            \
      acc[(mh) * 2 + _i][(nh) * 2 + _j] =                                       \
          __builtin_amdgcn_mfma_f32_16x16x32_bf16(                              \
              av[(mh) * 2 + _i][_k], BS[_j][_k],                                \
              acc[(mh) * 2 + _i][(nh) * 2 + _j], 0, 0, 0);                      \
  } while (0)

__global__ __launch_bounds__(512) void gemm3_kernel(
    const unsigned short* __restrict__ xo,
    const unsigned short* __restrict__ xee,
    const unsigned short* __restrict__ xeo,
    const unsigned short* __restrict__ Bo,
    const unsigned short* __restrict__ Bp,
    const unsigned short* __restrict__ Bq,
    float* __restrict__ out) {
  __shared__ __align__(16) unsigned short lds[40960];   // 80 KiB

  // bx 0..255: U (K=2048) -> breadth-first round 1 puts one U on every CU.
  const int bx = blockIdx.x;
  const unsigned short* A;
  const unsigned short* Bm;
  int K, row0, ncol0, col0;
  if (bx < 256) {
    A = xo;  Bm = Bo; K = 2048;
    row0 = (bx & 15) * 256; ncol0 = (bx >> 4) * 128; col0 = ncol0;
  } else if (bx < 384) {
    int b = bx - 256;
    A = xee; Bm = Bp; K = 1024;
    row0 = (b & 15) * 256; ncol0 = (b >> 4) * 128; col0 = 2048 + ncol0;
  } else {
    int b = bx - 384;
    A = xeo; Bm = Bq; K = 1024;
    row0 = (b & 15) * 256; ncol0 = (b >> 4) * 128; col0 = 3072 + ncol0;
  }
  const int NT = K >> 6;           // K-tiles of 64 (32 for U, 16 for P/Q)

  const int tid = threadIdx.x;
  const int lane = tid & 63;
  const int wave = tid >> 6;
  const int wm = wave >> 1;        // 0..3 : 64-row strip of C
  const int wn = wave & 1;         // 0..1 : 64-col strip of C
  const int lr = lane & 15, kq = lane >> 4;
  const int st_r = tid >> 3;                         // staging row 0..63
  const int st_c = ((tid & 7) ^ (st_r & 7)) * 8;     // pre-swizzled src chunk
  const int cA0 = (kq ^ (lr & 7)) * 8;               // swizzled ds_read chunks
  const int cA1 = ((4 + kq) ^ (lr & 7)) * 8;

  f32x4 acc[4][4];
#pragma unroll
  for (int i = 0; i < 4; ++i)
#pragma unroll
    for (int j = 0; j < 4; ++j)
      acc[i][j] = (f32x4){0.f, 0.f, 0.f, 0.f};
  short8 av[4][2], bv0[2][2], bv1[2][2];

  // Prologue: tile0 A -> buf0, B[0] -> B region; full drain.
  STAGEA(row0,       0, 0);
  STAGEA(row0 + 128, 0, 8192);
  STAGEB(ncol0,      0, 32768);
  STAGEB(ncol0 + 64, 0, 36864);
  W_VM0; PH_BAR;

  const int NITER = NT >> 1;
  for (int it = 0; it < NITER - 1; ++it) {
    const int t64 = it << 7;       // k-offset of tile t = 2*it
    // ---- tile t (buf0); stage A[t+1]->buf1, B[t+1] ----
    // p1: q(0,0); stage A[t+1]h0
    LOADA(0, 0); LOADB(bv0, 0);
    STAGEA(row0, t64 + 64, 16384);
    PH_BAR; W_LGKM0; PRIO1; MMAQ(bv0, 0, 0); PRIO0; PH_BAR;
    // p2: q(0,1); stage A[t+1]h1  (last B[t] read is here)
    LOADB(bv1, 1);
    STAGEA(row0 + 128, t64 + 64, 24576);
    PH_BAR; W_LGKM0; PRIO1; MMAQ(bv1, 0, 1); PRIO0; PH_BAR;
    // p3: q(1,1); stage B[t+1] (B reads sealed by p2 trailing barrier)
    LOADA(0, 1);
    STAGEB(ncol0,      t64 + 64, 32768);
    STAGEB(ncol0 + 64, t64 + 64, 36864);
    PH_BAR; W_LGKM0; PRIO1; MMAQ(bv1, 1, 1); PRIO0; PH_BAR;
    // p4: q(1,0); drain tile t+1 (A 4 + B 2 loads), barrier
    PRIO1; MMAQ(bv0, 1, 0); PRIO0; W_VM0; PH_BAR;
    // ---- tile t+1 (buf1); stage A[t+2]->buf0, B[t+2] ----
    // p5: q(0,0); stage A[t+2]h0
    LOADA(1, 0); LOADB(bv0, 0);
    STAGEA(row0, t64 + 128, 0);
    PH_BAR; W_LGKM0; PRIO1; MMAQ(bv0, 0, 0); PRIO0; PH_BAR;
    // p6: q(0,1); stage A[t+2]h1
    LOADB(bv1, 1);
    STAGEA(row0 + 128, t64 + 128, 8192);
    PH_BAR; W_LGKM0; PRIO1; MMAQ(bv1, 0, 1); PRIO0; PH_BAR;
    // p7: q(1,1); stage B[t+2]
    LOADA(1, 1);
    STAGEB(ncol0,      t64 + 128, 32768);
    STAGEB(ncol0 + 64, t64 + 128, 36864);
    PH_BAR; W_LGKM0; PRIO1; MMAQ(bv1, 1, 1); PRIO0; PH_BAR;
    // p8: q(1,0); drain tile t+2, barrier
    PRIO1; MMAQ(bv0, 1, 0); PRIO0; W_VM0; PH_BAR;
  }

  // Peeled last pair (tiles NT-2 -> buf0, NT-1 -> buf1): stage only A[NT-1]
  // and B[NT-1] during the first tile; tail barrier-free.
  {
    const int t64 = (NT - 2) << 6;
    LOADA(0, 0); LOADB(bv0, 0);
    STAGEA(row0, t64 + 64, 16384);
    PH_BAR; W_LGKM0; PRIO1; MMAQ(bv0, 0, 0); PRIO0; PH_BAR;
    LOADB(bv1, 1);
    STAGEA(row0 + 128, t64 + 64, 24576);
    PH_BAR; W_LGKM0; PRIO1; MMAQ(bv1, 0, 1); PRIO0; PH_BAR;
    LOADA(0, 1);
    STAGEB(ncol0,      t64 + 64, 32768);
    STAGEB(ncol0 + 64, t64 + 64, 36864);
    PH_BAR; W_LGKM0; PRIO1; MMAQ(bv1, 1, 1); PRIO0; PH_BAR;
    PRIO1; MMAQ(bv0, 1, 0); PRIO0; W_VM0; PH_BAR;
    // tile NT-1 (buf1): no staging, no cross-wave hazards -> no barriers
    LOADA(1, 0); LOADB(bv0, 0);
    W_LGKM0; PRIO1; MMAQ(bv0, 0, 0); PRIO0;
    LOADB(bv1, 1);
    W_LGKM0; PRIO1; MMAQ(bv1, 0, 1); PRIO0;
    LOADA(1, 1);
    W_LGKM0; PRIO1; MMAQ(bv1, 1, 1); MMAQ(bv0, 1, 0); PRIO0;
  }

  // C/D layout: col=lane&15, row=quad*4+reg
#pragma unroll
  for (int i = 0; i < 4; ++i)
#pragma unroll
    for (int j = 0; j < 4; ++j)
#pragma unroll
      for (int r = 0; r < 4; ++r) {
        int row = row0 + wm * 64 + i * 16 + kq * 4 + r;
        int col = col0 + wn * 64 + j * 16 + lr;
        out[(size_t)row * NN + col] = acc[i][j][r];
      }
}

// In-place combine, both fold levels. Row layout on entry:
// [0:2048)=u, [2048:3072)=p, [3072:4096)=q.
// v[k']=p+q, v[2047-k']=q-p (k'<1024); y[k]=v[k]+u[k], y[4095-k]=u[k]-v[k].
__global__ void combine_kernel(float* __restrict__ out) {
  int t = blockIdx.x * blockDim.x + threadIdx.x;   // 4096 rows * 128 threads
  int r = t >> 7;
  int k0 = (t & 127) * 4;                          // [0,512)
  float* row = out + (size_t)r * NN;
  float U0[4], U1[4], U2[4], U3[4], P0[4], P1[4], Q0[4], Q1[4];
  *(float4*)U0 = *(float4*)&row[k0];          // u[k0+e]
  *(float4*)U1 = *(float4*)&row[1020 - k0];   // u[1023-k'] rev
  *(float4*)U2 = *(float4*)&row[1024 + k0];   // u[1024+k0+e]
  *(float4*)U3 = *(float4*)&row[2044 - k0];   // u[2047-k'] rev
  *(float4*)P0 = *(float4*)&row[2048 + k0];   // p[k0+e]
  *(float4*)P1 = *(float4*)&row[3068 - k0];   // p[1023-k'] rev
  *(float4*)Q0 = *(float4*)&row[3072 + k0];   // q[k0+e]
  *(float4*)Q1 = *(float4*)&row[4092 - k0];   // q[1023-k'] rev
  float YA[4], YB[4], YC[4], YD[4], YE[4], YF[4], YG[4], YH[4];
#pragma unroll
  for (int e = 0; e < 4; ++e) {
    float v1 = P0[e] + Q0[e];        // v[k']
    float v2 = Q0[e] - P0[e];        // v[2047-k']
    float um = U3[3 - e];            // u[2047-k']
    YA[e] = v1 + U0[e];              // y[k']
    YB[3 - e] = U0[e] - v1;          // y[4095-k']
    YC[3 - e] = v2 + um;             // y[2047-k']
    YD[e] = um - v2;                 // y[2048+k']
    float pm = P1[3 - e], qm = Q1[3 - e];
    float w1 = pm + qm;              // v[1023-k']
    float w2 = qm - pm;              // v[1024+k']
    float umm = U1[3 - e];           // u[1023-k']
    YE[3 - e] = w1 + umm;            // y[1023-k']
    YF[e] = umm - w1;                // y[3072+k']
    YG[e] = w2 + U2[e];              // y[1024+k']
    YH[3 - e] = U2[e] - w2;          // y[3071-k']
  }
  *(float4*)&row[k0] = *(float4*)YA;
  *(float4*)&row[4092 - k0] = *(float4*)YB;
  *(float4*)&row[2044 - k0] = *(float4*)YC;
  *(float4*)&row[2048 + k0] = *(float4*)YD;
  *(float4*)&row[1020 - k0] = *(float4*)YE;
  *(float4*)&row[3072 + k0] = *(float4*)YF;
  *(float4*)&row[1024 + k0] = *(float4*)YG;
  *(float4*)&row[3068 - k0] = *(float4*)YH;
}

extern "C" void kernel_launch(void* const* d_in, const int* in_sizes, int n_in,
                              void* d_out, int out_size, void* d_ws, size_t ws_size,
                              hipStream_t stream) {
  const float* x = (const float*)d_in[0];
  float* out = (float*)d_out;
  unsigned short* xo  = (unsigned short*)d_ws;            // 16 MB
  unsigned short* xee = xo + (size_t)NN * 2048;           // 8 MB
  unsigned short* xeo = xee + (size_t)NN * 1024;          // 8 MB
  unsigned short* Bo  = xeo + (size_t)NN * 1024;          // 8 MB
  unsigned short* Bp  = Bo + (size_t)2048 * 2048;         // 2 MB
  unsigned short* Bq  = Bp + (size_t)1024 * 1024;         // 2 MB -> 44 MB total

  int prep_threads = NXS + NBO + 2 * NBP;
  prep_kernel<<<prep_threads / 256, 256, 0, stream>>>(x, xo, xee, xeo, Bo, Bp, Bq);

  gemm3_kernel<<<512, 512, 0, stream>>>(xo, xee, xeo, Bo, Bp, Bq, out);

  combine_kernel<<<NN * 128 / 256, 256, 0, stream>>>(out);
}